// Round 1
// baseline (728.597 us; speedup 1.0000x reference)
//
#include <hip/hip_runtime.h>

#define Bx 8
#define Nx 256
#define Lx 48
#define Fx 96

// ---------------------------------------------------------------------------
// K1: per-(b,r) rowsum[b,r,l] = sum_j x[b,r,j,l]; colsum[b,r,l] = sum_i x[b,i,r,l];
//     diag[b,r,l] = x[b,r,r,l]
// ---------------------------------------------------------------------------
__global__ __launch_bounds__(192) void k1_reduce(const float* __restrict__ x,
                                                 float* __restrict__ rowsum,
                                                 float* __restrict__ colsum,
                                                 float* __restrict__ diagv) {
    const int blk = blockIdx.x;           // b*N + r
    const int b = blk >> 8;
    const int r = blk & 255;
    const int t = threadIdx.x;
    const int l = t % Lx;                 // 0..47
    const int g = t / Lx;                 // 0..3
    __shared__ float red[192];

    const size_t base  = (size_t)blk * Nx * Lx;                    // x[b][r][0][0]
    const size_t cbase = (size_t)b * Nx * Nx * Lx + (size_t)r * Lx; // x[b][0][r][0]

    float accR = 0.f;
    for (int j = g; j < Nx; j += 4)
        accR += x[base + (size_t)j * Lx + l];
    red[t] = accR;
    __syncthreads();
    if (g == 0)
        rowsum[(size_t)blk * Lx + l] = red[l] + red[48 + l] + red[96 + l] + red[144 + l];
    __syncthreads();

    float accC = 0.f;
    for (int i = g; i < Nx; i += 4)
        accC += x[cbase + (size_t)i * Nx * Lx + l];
    red[t] = accC;
    __syncthreads();
    if (g == 0)
        colsum[(size_t)blk * Lx + l] = red[l] + red[48 + l] + red[96 + l] + red[144 + l];

    if (t < Lx)
        diagv[(size_t)blk * Lx + t] = x[base + (size_t)r * Lx + t];
}

// ---------------------------------------------------------------------------
// K1b: trace[b,l] = sum_i diag[b,i,l]; totsum[b,l] = sum_i rowsum[b,i,l]
// ---------------------------------------------------------------------------
__global__ __launch_bounds__(64) void k1b_trace(const float* __restrict__ rowsum,
                                                const float* __restrict__ diagv,
                                                float* __restrict__ trace,
                                                float* __restrict__ totsum) {
    const int b = blockIdx.x;
    const int l = threadIdx.x;
    if (l >= Lx) return;
    float tr = 0.f, ts = 0.f;
    for (int i = 0; i < Nx; ++i) {
        const size_t idx = (size_t)(b * Nx + i) * Lx + l;
        tr += diagv[idx];
        ts += rowsum[idx];
    }
    trace[b * Lx + l]  = tr;
    totsum[b * Lx + l] = ts;
}

// ---------------------------------------------------------------------------
// K2: per-(b,n) f-vectors:
//   add_d[b,n,f] = diag.w0 + rowsum.w1 + colsum.w2 + trace.w3 + totsum.w4   (i==j only)
//   add_j[b,n,f] = diag.w5 + rowsum.w6 + colsum.w7                          (indexed by j)
//   add_i[b,n,f] = diag.w8 + rowsum.w9 + colsum.w10 + trace.w13 + totsum.w14 (indexed by i; global term folded)
// ---------------------------------------------------------------------------
__global__ __launch_bounds__(128) void k2_vectors(const float* __restrict__ w,
                                                  const float* __restrict__ rowsum,
                                                  const float* __restrict__ colsum,
                                                  const float* __restrict__ diagv,
                                                  const float* __restrict__ trace,
                                                  const float* __restrict__ totsum,
                                                  float* __restrict__ add_i,
                                                  float* __restrict__ add_j,
                                                  float* __restrict__ add_d) {
    const int blk = blockIdx.x;           // b*N + n
    const int b = blk >> 8;
    const int f = threadIdx.x;
    if (f >= Fx) return;

    const float* dP  = diagv  + (size_t)blk * Lx;
    const float* rP  = rowsum + (size_t)blk * Lx;
    const float* cP  = colsum + (size_t)blk * Lx;
    const float* trP = trace  + b * Lx;
    const float* tsP = totsum + b * Lx;

    float ai = 0.f, aj = 0.f, ad = 0.f;
    #pragma unroll 4
    for (int l = 0; l < Lx; ++l) {
        const float d  = dP[l];
        const float r  = rP[l];
        const float c  = cP[l];
        const float tr = trP[l];
        const float ts = tsP[l];
        const float* wl = w + (size_t)l * Fx + f;
        ad = fmaf(d,  wl[0  * Lx * Fx], ad);
        ad = fmaf(r,  wl[1  * Lx * Fx], ad);
        ad = fmaf(c,  wl[2  * Lx * Fx], ad);
        ad = fmaf(tr, wl[3  * Lx * Fx], ad);
        ad = fmaf(ts, wl[4  * Lx * Fx], ad);
        aj = fmaf(d,  wl[5  * Lx * Fx], aj);
        aj = fmaf(r,  wl[6  * Lx * Fx], aj);
        aj = fmaf(c,  wl[7  * Lx * Fx], aj);
        ai = fmaf(d,  wl[8  * Lx * Fx], ai);
        ai = fmaf(r,  wl[9  * Lx * Fx], ai);
        ai = fmaf(c,  wl[10 * Lx * Fx], ai);
        ai = fmaf(tr, wl[13 * Lx * Fx], ai);
        ai = fmaf(ts, wl[14 * Lx * Fx], ai);
    }
    add_i[(size_t)blk * Fx + f] = ai;
    add_j[(size_t)blk * Fx + f] = aj;
    add_d[(size_t)blk * Fx + f] = ad;
}

// ---------------------------------------------------------------------------
// K3: main dense pass. Block = (b,i) [2048 blocks], thread = j [256].
//   out[b,i,j,f] = xij . w12[:,f] + xji . w11[:,f]
//                + add_i[b,i,f] + add_j[b,j,f] + (i==j) * add_d[b,i,f]
// w / add_i / add_d indices are wave-uniform -> scalar loads (SMEM pipe).
// ---------------------------------------------------------------------------
__global__ __launch_bounds__(256) void k3_main(const float* __restrict__ x,
                                               const float* __restrict__ w,
                                               const float* __restrict__ add_i,
                                               const float* __restrict__ add_j,
                                               const float* __restrict__ add_d,
                                               float* __restrict__ out) {
    const int blk = blockIdx.x;           // b*N + i  (uniform)
    const int b = blk >> 8;
    const int i = blk & 255;
    const int j = threadIdx.x;            // divergent

    const size_t p = (size_t)blk * Nx + j;                    // b*N*N + i*N + j
    const size_t q = ((size_t)(b * Nx + j)) * Nx + i;         // b*N*N + j*N + i

    float xij[Lx], xji[Lx];
    const float4* xp = (const float4*)(x + p * Lx);
    const float4* xq = (const float4*)(x + q * Lx);
    #pragma unroll
    for (int l4 = 0; l4 < Lx / 4; ++l4) {
        float4 a = xp[l4];
        xij[4 * l4 + 0] = a.x; xij[4 * l4 + 1] = a.y;
        xij[4 * l4 + 2] = a.z; xij[4 * l4 + 3] = a.w;
        float4 c = xq[l4];
        xji[4 * l4 + 0] = c.x; xji[4 * l4 + 1] = c.y;
        xji[4 * l4 + 2] = c.z; xji[4 * l4 + 3] = c.w;
    }

    const float* w11 = w + 11 * Lx * Fx;
    const float* w12 = w + 12 * Lx * Fx;
    const float* aiP = add_i + (size_t)blk * Fx;              // uniform
    const float* adP = add_d + (size_t)blk * Fx;              // uniform
    const float* ajP = add_j + (size_t)(b * Nx + j) * Fx;     // divergent
    const float  de  = (i == j) ? 1.f : 0.f;
    float* op = out + p * Fx;

    #pragma unroll 1
    for (int fc = 0; fc < Fx; fc += 16) {
        float acc[16];
        #pragma unroll
        for (int ff = 0; ff < 16; ++ff) {
            const int f = fc + ff;
            acc[ff] = aiP[f] + ajP[f] + de * adP[f];
        }
        #pragma unroll
        for (int l = 0; l < Lx; ++l) {
            const float a  = xij[l];
            const float c2 = xji[l];
            const float* w12l = w12 + l * Fx + fc;
            const float* w11l = w11 + l * Fx + fc;
            #pragma unroll
            for (int ff = 0; ff < 16; ++ff)
                acc[ff] = fmaf(a, w12l[ff], fmaf(c2, w11l[ff], acc[ff]));
        }
        #pragma unroll
        for (int qq = 0; qq < 4; ++qq) {
            float4 v = make_float4(acc[4 * qq + 0], acc[4 * qq + 1],
                                   acc[4 * qq + 2], acc[4 * qq + 3]);
            ((float4*)(op + fc))[qq] = v;
        }
    }
}

// ---------------------------------------------------------------------------
extern "C" void kernel_launch(void* const* d_in, const int* in_sizes, int n_in,
                              void* d_out, int out_size, void* d_ws, size_t ws_size,
                              hipStream_t stream) {
    const float* x = (const float*)d_in[0];
    const float* w = (const float*)d_in[1];
    float* out = (float*)d_out;

    float* ws      = (float*)d_ws;
    float* rowsum  = ws;                                  // B*N*L = 98304
    float* colsum  = rowsum + (size_t)Bx * Nx * Lx;
    float* diagv   = colsum + (size_t)Bx * Nx * Lx;
    float* trace   = diagv  + (size_t)Bx * Nx * Lx;       // B*L = 384
    float* totsum  = trace  + (size_t)Bx * Lx;
    float* add_i   = totsum + (size_t)Bx * Lx;            // B*N*F = 196608
    float* add_j   = add_i  + (size_t)Bx * Nx * Fx;
    float* add_d   = add_j  + (size_t)Bx * Nx * Fx;

    k1_reduce<<<Bx * Nx, 192, 0, stream>>>(x, rowsum, colsum, diagv);
    k1b_trace<<<Bx, 64, 0, stream>>>(rowsum, diagv, trace, totsum);
    k2_vectors<<<Bx * Nx, 128, 0, stream>>>(w, rowsum, colsum, diagv, trace, totsum,
                                            add_i, add_j, add_d);
    k3_main<<<Bx * Nx, 256, 0, stream>>>(x, w, add_i, add_j, add_d, out);
}

// Round 2
// 409.745 us; speedup vs baseline: 1.7782x; 1.7782x over previous
//
#include <hip/hip_runtime.h>

#define Bx 8
#define Nx 256
#define Lx 48
#define Fx 96
#define KK 96      // concatenated K: [xij(48) | xji(48)]
#define KP 104     // padded K stride in bf16 units (208 B, 16B-aligned)

typedef __attribute__((ext_vector_type(8))) short bf16x8;
typedef __attribute__((ext_vector_type(4))) float f32x4;

__device__ __forceinline__ unsigned short f2bf(float f) {
    unsigned int u = __float_as_uint(f);
    u += 0x7fffu + ((u >> 16) & 1u);       // RNE
    return (unsigned short)(u >> 16);
}
__device__ __forceinline__ unsigned int pack2(float a, float b) {
    return (unsigned int)f2bf(a) | ((unsigned int)f2bf(b) << 16);
}

// ---------------------------------------------------------------------------
// K_row: rowsum[b,i,l] = sum_j x[b,i,j,l] (contiguous); diag[b,i,l] = x[b,i,i,l]
// ---------------------------------------------------------------------------
__global__ __launch_bounds__(192) void k_row(const float* __restrict__ x,
                                             float* __restrict__ rowsum,
                                             float* __restrict__ diagv) {
    const int blk = blockIdx.x;           // b*N + i
    const int t = threadIdx.x;
    const int l = t % Lx;
    const int g = t / Lx;
    __shared__ float red[192];
    const size_t base = (size_t)blk * Nx * Lx;
    float acc = 0.f;
    for (int j = g; j < Nx; j += 4)
        acc += x[base + (size_t)j * Lx + l];
    red[t] = acc;
    __syncthreads();
    if (g == 0)
        rowsum[(size_t)blk * Lx + l] = red[l] + red[48 + l] + red[96 + l] + red[144 + l];
    if (t < Lx)
        diagv[(size_t)blk * Lx + t] = x[base + (size_t)(blk & 255) * Lx + t];
}

// ---------------------------------------------------------------------------
// K_col: colsum[b,j,l] = sum_i x[b,i,j,l]. Coalesced: block owns a 16-j chunk
// (16*48 = 768 contiguous floats per i), accumulates 32 i's, atomicAdd out.
// Grid = B * 16 jc * 8 isplit = 1024.  colsum must be zeroed first.
// ---------------------------------------------------------------------------
__global__ __launch_bounds__(256) void k_col(const float* __restrict__ x,
                                             float* __restrict__ colsum) {
    const int blk = blockIdx.x;
    const int is = blk & 7;
    const int jc = (blk >> 3) & 15;
    const int b  = blk >> 7;
    const int t = threadIdx.x;
    const size_t cb = (size_t)b * Nx * Nx * Lx + (size_t)jc * 16 * Lx;
    float a0 = 0.f, a1 = 0.f, a2 = 0.f;
    for (int ii = 0; ii < 32; ++ii) {
        const int i = is * 32 + ii;
        const float* p = x + cb + (size_t)i * Nx * Lx;
        a0 += p[t];
        a1 += p[t + 256];
        a2 += p[t + 512];
    }
    float* c = colsum + ((size_t)b * Nx + jc * 16) * Lx;
    atomicAdd(c + t, a0);
    atomicAdd(c + t + 256, a1);
    atomicAdd(c + t + 512, a2);
}

// ---------------------------------------------------------------------------
// K1b: trace[b,l] = sum_i diag[b,i,l]; totsum[b,l] = sum_i rowsum[b,i,l]
// ---------------------------------------------------------------------------
__global__ __launch_bounds__(64) void k1b_trace(const float* __restrict__ rowsum,
                                                const float* __restrict__ diagv,
                                                float* __restrict__ trace,
                                                float* __restrict__ totsum) {
    const int b = blockIdx.x;
    const int l = threadIdx.x;
    if (l >= Lx) return;
    float tr = 0.f, ts = 0.f;
    for (int i = 0; i < Nx; ++i) {
        const size_t idx = (size_t)(b * Nx + i) * Lx + l;
        tr += diagv[idx];
        ts += rowsum[idx];
    }
    trace[b * Lx + l]  = tr;
    totsum[b * Lx + l] = ts;
}

// ---------------------------------------------------------------------------
// K2: per-(b,n) f-vectors (fp32 exact):
//   add_d = diag.w0 + rowsum.w1 + colsum.w2 + trace.w3 + totsum.w4
//   add_j = diag.w5 + rowsum.w6 + colsum.w7
//   add_i = diag.w8 + rowsum.w9 + colsum.w10 + trace.w13 + totsum.w14
// ---------------------------------------------------------------------------
__global__ __launch_bounds__(128) void k2_vectors(const float* __restrict__ w,
                                                  const float* __restrict__ rowsum,
                                                  const float* __restrict__ colsum,
                                                  const float* __restrict__ diagv,
                                                  const float* __restrict__ trace,
                                                  const float* __restrict__ totsum,
                                                  float* __restrict__ add_i,
                                                  float* __restrict__ add_j,
                                                  float* __restrict__ add_d) {
    const int blk = blockIdx.x;           // b*N + n
    const int b = blk >> 8;
    const int f = threadIdx.x;
    if (f >= Fx) return;

    const float* dP  = diagv  + (size_t)blk * Lx;
    const float* rP  = rowsum + (size_t)blk * Lx;
    const float* cP  = colsum + (size_t)blk * Lx;
    const float* trP = trace  + b * Lx;
    const float* tsP = totsum + b * Lx;

    float ai = 0.f, aj = 0.f, ad = 0.f;
    #pragma unroll 4
    for (int l = 0; l < Lx; ++l) {
        const float d  = dP[l];
        const float r  = rP[l];
        const float c  = cP[l];
        const float tr = trP[l];
        const float ts = tsP[l];
        const float* wl = w + (size_t)l * Fx + f;
        ad = fmaf(d,  wl[0  * Lx * Fx], ad);
        ad = fmaf(r,  wl[1  * Lx * Fx], ad);
        ad = fmaf(c,  wl[2  * Lx * Fx], ad);
        ad = fmaf(tr, wl[3  * Lx * Fx], ad);
        ad = fmaf(ts, wl[4  * Lx * Fx], ad);
        aj = fmaf(d,  wl[5  * Lx * Fx], aj);
        aj = fmaf(r,  wl[6  * Lx * Fx], aj);
        aj = fmaf(c,  wl[7  * Lx * Fx], aj);
        ai = fmaf(d,  wl[8  * Lx * Fx], ai);
        ai = fmaf(r,  wl[9  * Lx * Fx], ai);
        ai = fmaf(c,  wl[10 * Lx * Fx], ai);
        ai = fmaf(tr, wl[13 * Lx * Fx], ai);
        ai = fmaf(ts, wl[14 * Lx * Fx], ai);
    }
    add_i[(size_t)blk * Fx + f] = ai;
    add_j[(size_t)blk * Fx + f] = aj;
    add_d[(size_t)blk * Fx + f] = ad;
}

// ---------------------------------------------------------------------------
// K_w: wt[f][kk] (bf16, padded stride KP): kk<48 -> w12[kk][f], kk<96 -> w11[kk-48][f]
// ---------------------------------------------------------------------------
__global__ __launch_bounds__(256) void k_w(const float* __restrict__ w,
                                           unsigned short* __restrict__ wt) {
    const int idx = blockIdx.x * 256 + threadIdx.x;
    if (idx >= Fx * KP) return;
    const int f = idx / KP, kk = idx % KP;
    float v = 0.f;
    if (kk < 48)      v = w[12 * Lx * Fx + kk * Fx + f];
    else if (kk < 96) v = w[11 * Lx * Fx + (kk - 48) * Fx + f];
    wt[idx] = f2bf(v);
}

// ---------------------------------------------------------------------------
// K3: MFMA dense pass. Block = (b, i, j-tile of 64). M=64 (j), N=96 (f), K=96.
//   out[b,i,j,f] = [xij|xji] . wt^T + add_i[b,i,f] + add_j[b,j,f] + (i==j)add_d
// A staged to LDS as bf16 [64][KP]; B (wt) bulk-copied [96][KP].
// mfma_f32_16x16x32_bf16: A[m=lane&15][k=quad*8+e], B[k=quad*8+e][n=lane&15],
// D: row m = quad*4+reg, col n = lane&15.
// ---------------------------------------------------------------------------
__global__ __launch_bounds__(256) void k3_mfma(const float* __restrict__ x,
                                               const unsigned short* __restrict__ wt,
                                               const float* __restrict__ add_i,
                                               const float* __restrict__ add_j,
                                               const float* __restrict__ add_d,
                                               float* __restrict__ out) {
    __shared__ unsigned short Al[64 * KP];   // 13312 B
    __shared__ unsigned short Bl[96 * KP];   // 19968 B
    const int blk = blockIdx.x;              // (b*N + i)*4 + jt
    const int jt = blk & 3;
    const int bi = blk >> 2;                 // b*N + i
    const int b  = bi >> 8;
    const int i  = bi & 255;
    const int j0 = jt * 64;
    const int t  = threadIdx.x;

    // stage B: 96*KP bf16 = 1248 uint4
    {
        const uint4* src = (const uint4*)wt;
        uint4* dst = (uint4*)Bl;
        #pragma unroll
        for (int it = 0; it < 5; ++it) {
            const int idx = t + it * 256;
            if (idx < (96 * KP * 2) / 16) dst[idx] = src[idx];
        }
    }
    // stage A: row r = t/4, quarter q = t&3; float4 index q + 4e (coalesced)
    {
        const int r = t >> 2, q = t & 3;
        const float* pij = x + ((size_t)bi * Nx + j0 + r) * Lx;
        const float* pji = x + ((size_t)(b * Nx + j0 + r) * Nx + i) * Lx;
        unsigned int* arow = (unsigned int*)Al + r * (KP / 2);
        #pragma unroll
        for (int e = 0; e < 3; ++e) {
            const float4 v = *(const float4*)(pij + q * 4 + e * 16);
            arow[q * 2 + e * 8 + 0] = pack2(v.x, v.y);
            arow[q * 2 + e * 8 + 1] = pack2(v.z, v.w);
        }
        #pragma unroll
        for (int e = 0; e < 3; ++e) {
            const float4 v = *(const float4*)(pji + q * 4 + e * 16);
            arow[24 + q * 2 + e * 8 + 0] = pack2(v.x, v.y);
            arow[24 + q * 2 + e * 8 + 1] = pack2(v.z, v.w);
        }
    }
    __syncthreads();

    const int wave = t >> 6, lane = t & 63;
    const int lm = lane & 15, quad = lane >> 4;
    const int m0 = wave * 16;

    bf16x8 afr[3];
    #pragma unroll
    for (int ks = 0; ks < 3; ++ks)
        afr[ks] = *(const bf16x8*)(Al + (m0 + lm) * KP + ks * 32 + quad * 8);

    f32x4 acc[6];
    #pragma unroll
    for (int nt = 0; nt < 6; ++nt) {
        f32x4 c = {0.f, 0.f, 0.f, 0.f};
        #pragma unroll
        for (int ks = 0; ks < 3; ++ks) {
            const bf16x8 bfr = *(const bf16x8*)(Bl + (nt * 16 + lm) * KP + ks * 32 + quad * 8);
            c = __builtin_amdgcn_mfma_f32_16x16x32_bf16(afr[ks], bfr, c, 0, 0, 0);
        }
        acc[nt] = c;
    }

    // epilogue
    const float* aiP = add_i + (size_t)bi * Fx;
    const float* adP = add_d + (size_t)bi * Fx;
    float* outP = out + (size_t)bi * Nx * Fx;
    #pragma unroll
    for (int nt = 0; nt < 6; ++nt) {
        const int f = nt * 16 + lm;
        const float ai = aiP[f];
        #pragma unroll
        for (int reg = 0; reg < 4; ++reg) {
            const int j = j0 + m0 + quad * 4 + reg;
            float v = acc[nt][reg] + ai + add_j[((size_t)(b * Nx) + j) * Fx + f];
            if (j == i) v += adP[f];
            outP[(size_t)j * Fx + f] = v;
        }
    }
}

// ---------------------------------------------------------------------------
extern "C" void kernel_launch(void* const* d_in, const int* in_sizes, int n_in,
                              void* d_out, int out_size, void* d_ws, size_t ws_size,
                              hipStream_t stream) {
    const float* x = (const float*)d_in[0];
    const float* w = (const float*)d_in[1];
    float* out = (float*)d_out;

    float* ws      = (float*)d_ws;
    float* rowsum  = ws;                                  // B*N*L
    float* colsum  = rowsum + (size_t)Bx * Nx * Lx;
    float* diagv   = colsum + (size_t)Bx * Nx * Lx;
    float* trace   = diagv  + (size_t)Bx * Nx * Lx;       // B*L
    float* totsum  = trace  + (size_t)Bx * Lx;
    float* add_i   = totsum + (size_t)Bx * Lx;            // B*N*F
    float* add_j   = add_i  + (size_t)Bx * Nx * Fx;
    float* add_d   = add_j  + (size_t)Bx * Nx * Fx;
    unsigned short* wtbf = (unsigned short*)(add_d + (size_t)Bx * Nx * Fx);

    k_row<<<Bx * Nx, 192, 0, stream>>>(x, rowsum, diagv);
    hipMemsetAsync(colsum, 0, (size_t)Bx * Nx * Lx * sizeof(float), stream);
    k_col<<<Bx * 16 * 8, 256, 0, stream>>>(x, colsum);
    k1b_trace<<<Bx, 64, 0, stream>>>(rowsum, diagv, trace, totsum);
    k2_vectors<<<Bx * Nx, 128, 0, stream>>>(w, rowsum, colsum, diagv, trace, totsum,
                                            add_i, add_j, add_d);
    k_w<<<(Fx * KP + 255) / 256, 256, 0, stream>>>(w, wtbf);
    k3_mfma<<<Bx * Nx * 4, 256, 0, stream>>>(x, wtbf, add_i, add_j, add_d, out);
}